// Round 1
// baseline (44.040 us; speedup 1.0000x reference)
//
#include <hip/hip_runtime.h>
#include <math.h>

#define EMBED 64
#define TB 32          // batch elements per block
#define BATCH 16384

__global__ __launch_bounds__(256, 2) void ncf_fused(
    const int* __restrict__ user, const int* __restrict__ item,
    const int* __restrict__ p1, const int* __restrict__ p2,
    const int* __restrict__ p3, const int* __restrict__ p4, const int* __restrict__ p5,
    const float* __restrict__ Wu, const float* __restrict__ bu,
    const float* __restrict__ Wi, const float* __restrict__ bi,
    const float* __restrict__ W1, const float* __restrict__ b1,
    const float* __restrict__ W2, const float* __restrict__ b2,
    const float* __restrict__ W3, const float* __restrict__ b3,
    float* __restrict__ out)
{
    __shared__ float xs[TB][128];    // x = [pu, ei]; later reused as h2t[64][33]
    __shared__ float h1s[TB][128];

    const int t    = threadIdx.x;
    const int lane = t & 63;
    const int wv   = t >> 6;     // 0..3
    const int blk  = blockIdx.x;

    // ---------------- Phase 1: embeddings + attention ----------------
    const float bu_l = bu[lane];
    const float bi_l = bi[lane];

    #pragma unroll
    for (int e = 0; e < TB / 4; ++e) {          // 8 elements per wave
        const int b  = wv * (TB / 4) + e;
        const int gb = blk * TB + b;

        const int iu = user[gb];
        const int ii = item[gb];
        int ip[5];
        ip[0] = p1[gb]; ip[1] = p2[gb]; ip[2] = p3[gb]; ip[3] = p4[gb]; ip[4] = p5[gb];

        const float eu = fmaxf(Wu[(size_t)iu * EMBED + lane] + bu_l, 0.0f);
        const float ei = fmaxf(Wi[(size_t)ii * EMBED + lane] + bi_l, 0.0f);

        float ep[5], w[5];
        #pragma unroll
        for (int k = 0; k < 5; ++k) {
            ep[k] = fmaxf(Wi[(size_t)ip[k] * EMBED + lane] + bi_l, 0.0f);
            w[k]  = ei * ep[k];
        }

        // butterfly reduce each dot across the 64-lane wave
        #pragma unroll
        for (int k = 0; k < 5; ++k) {
            float v = w[k];
            #pragma unroll
            for (int off = 32; off >= 1; off >>= 1)
                v += __shfl_xor(v, off, 64);
            w[k] = v;
        }

        // stable softmax over 5 (replicated per lane)
        float m = w[0];
        #pragma unroll
        for (int k = 1; k < 5; ++k) m = fmaxf(m, w[k]);
        float z[5], s = 0.0f;
        #pragma unroll
        for (int k = 0; k < 5; ++k) { z[k] = expf(w[k] - m); s += z[k]; }
        const float inv_s = 1.0f / s;

        float pum = 0.0f;
        #pragma unroll
        for (int k = 0; k < 5; ++k) pum += z[k] * ep[k];
        pum *= inv_s;

        const float pu = eu + 0.2f * pum;
        xs[b][lane]      = pu;
        xs[b][64 + lane] = ei;
    }

    __syncthreads();

    // ---------------- Phase 2: layer 1  (h1 = relu(X @ W1^T + b1)) ----------------
    // thread -> 2 output cols (o0, o0+64) x 8 elements (quarter q)
    {
        const int o0 = t & 63;
        const int o1 = o0 + 64;
        const int q  = t >> 6;                 // 0..3 (== wave id)

        float acc0[8], acc1[8];
        const float bb0 = b1[o0], bb1 = b1[o1];
        #pragma unroll
        for (int b = 0; b < 8; ++b) { acc0[b] = bb0; acc1[b] = bb1; }

        for (int kk = 0; kk < 128; kk += 16) {
            float4 wa[4], wb[4];
            const float4* wpa = reinterpret_cast<const float4*>(&W1[o0 * 128 + kk]);
            const float4* wpb = reinterpret_cast<const float4*>(&W1[o1 * 128 + kk]);
            #pragma unroll
            for (int j = 0; j < 4; ++j) { wa[j] = wpa[j]; wb[j] = wpb[j]; }

            #pragma unroll
            for (int b = 0; b < 8; ++b) {
                const float4* xp = reinterpret_cast<const float4*>(&xs[q * 8 + b][kk]);
                #pragma unroll
                for (int j = 0; j < 4; ++j) {
                    const float4 xv = xp[j];
                    acc0[b] += xv.x * wa[j].x + xv.y * wa[j].y + xv.z * wa[j].z + xv.w * wa[j].w;
                    acc1[b] += xv.x * wb[j].x + xv.y * wb[j].y + xv.z * wb[j].z + xv.w * wb[j].w;
                }
            }
        }

        #pragma unroll
        for (int b = 0; b < 8; ++b) {
            h1s[q * 8 + b][o0] = fmaxf(acc0[b], 0.0f);
            h1s[q * 8 + b][o1] = fmaxf(acc1[b], 0.0f);
        }
    }

    __syncthreads();   // h1s ready; xs free for reuse

    // ---------------- Phase 3: layer 2  (h2 = relu(H1 @ W2^T + b2)) ----------------
    // h2 stored transposed with pad: h2t[o2][b], stride 33 (reuses xs memory)
    float* h2t = &xs[0][0];
    {
        const int oa = t & 31;
        const int ob = oa + 32;
        const int g  = t >> 5;                 // 0..7, 4 elements each

        float acca[4], accb[4];
        const float ba = b2[oa], bbv = b2[ob];
        #pragma unroll
        for (int b = 0; b < 4; ++b) { acca[b] = ba; accb[b] = bbv; }

        for (int kk = 0; kk < 128; kk += 16) {
            float4 wa[4], wb[4];
            const float4* wpa = reinterpret_cast<const float4*>(&W2[oa * 128 + kk]);
            const float4* wpb = reinterpret_cast<const float4*>(&W2[ob * 128 + kk]);
            #pragma unroll
            for (int j = 0; j < 4; ++j) { wa[j] = wpa[j]; wb[j] = wpb[j]; }

            #pragma unroll
            for (int b = 0; b < 4; ++b) {
                const float4* xp = reinterpret_cast<const float4*>(&h1s[g * 4 + b][kk]);
                #pragma unroll
                for (int j = 0; j < 4; ++j) {
                    const float4 xv = xp[j];
                    acca[b] += xv.x * wa[j].x + xv.y * wa[j].y + xv.z * wa[j].z + xv.w * wa[j].w;
                    accb[b] += xv.x * wb[j].x + xv.y * wb[j].y + xv.z * wb[j].z + xv.w * wb[j].w;
                }
            }
        }

        #pragma unroll
        for (int b = 0; b < 4; ++b) {
            const int bl = g * 4 + b;
            h2t[oa * 33 + bl] = fmaxf(acca[b], 0.0f);
            h2t[ob * 33 + bl] = fmaxf(accb[b], 0.0f);
        }
    }

    __syncthreads();

    // ---------------- Phase 4: layer 3 + sigmoid ----------------
    if (t < TB) {
        float acc = b3[0];
        #pragma unroll
        for (int j = 0; j < 64; ++j)
            acc += h2t[j * 33 + t] * W3[j];
        out[blk * TB + t] = 1.0f / (1.0f + expf(-acc));
    }
}

extern "C" void kernel_launch(void* const* d_in, const int* in_sizes, int n_in,
                              void* d_out, int out_size, void* d_ws, size_t ws_size,
                              hipStream_t stream) {
    const int*   user = (const int*)  d_in[0];
    const int*   item = (const int*)  d_in[1];
    const int*   p1   = (const int*)  d_in[2];
    const int*   p2   = (const int*)  d_in[3];
    const int*   p3   = (const int*)  d_in[4];
    const int*   p4   = (const int*)  d_in[5];
    const int*   p5   = (const int*)  d_in[6];
    const float* Wu   = (const float*)d_in[7];
    const float* bu   = (const float*)d_in[8];
    const float* Wi   = (const float*)d_in[9];
    const float* bi   = (const float*)d_in[10];
    const float* W1   = (const float*)d_in[11];
    const float* b1   = (const float*)d_in[12];
    const float* W2   = (const float*)d_in[13];
    const float* b2   = (const float*)d_in[14];
    const float* W3   = (const float*)d_in[15];
    const float* b3   = (const float*)d_in[16];
    float* out = (float*)d_out;

    dim3 grid(BATCH / TB);
    dim3 block(256);
    hipLaunchKernelGGL(ncf_fused, grid, block, 0, stream,
                       user, item, p1, p2, p3, p4, p5,
                       Wu, bu, Wi, bi, W1, b1, W2, b2, W3, b3, out);
}